// Round 7
// baseline (45156.741 us; speedup 1.0000x reference)
//
#include <hip/hip_runtime.h>
#include <math.h>

// BatchFrechetMean: inductive geodesic mean of 256 SPD 256x256 matrices.
// Eigh-free Chebyshev evaluation of M^{-1/2} and S^t, persistent SINGLE-XCD
// kernel, PLAIN-CACHED data plane (R9, verified) + FLAT FLAG barrier (new).
//
// R10. R9 results: FETCH 12.6->2.0 GB (single-XCD L2-resident data plane
// works; placement/election verified by correctness of write-back stores),
// dur 44.9ms = 11.7us/round. Data phase accounts for ~4us; the rest is the
// barrier: 32 SERIALIZED agent(MALL)-scope fetch-adds + publish hop + MALL
// spin. Fix: flat flag barrier. flags[32] in ONE 128B line; arrival = one
// fire-and-forget agent atomic store (stores pipeline, no RMW round-trip
// chain); detection = each wave loads all 32 flags in ONE vector load
// (lanes 0..31) + __all(fv>=n); no publish hop; no trailing __syncthreads
// (each wave polls, then buffer_inv's its own CU L1). Data plane, math,
// geometry identical to R9.
//
// Measured HW facts driving this design:
//  - sc0/sc1 data accesses are MALL-serviced on gfx950 (R7/R8c: FETCH ~= full
//    operand stream) -> data plane must use PLAIN cached accesses.
//  - Plain write-back stores are visible to other blocks ONLY via shared L2
//    -> R9 passing proves all participants land on one XCD (election works).
//  - Agent-scope atomics are placement-independent -> barrier cannot hang.
//
// Spectral bounds (provable): lambda(f) in [1, ~5.2] => lambda(M) in [1, 5.5],
// lambda(S) in [1/5.75, 5.75]. Approximation intervals with margin:
//   x^{-1/2} on [0.95, 5.75], deg 11 (s=4, m=2)  -> err ~3e-5
//   x^{t}    on [0.17, 5.90], deg 39 (s=8, m=4)  -> err ~1e-6
//
// Perf history: R5 64blk agent fences 41.1ms -> R6 102.5 -> R7 51 -> R8c 72
// -> R9 single-XCD plain plane 44.9ms -> R10 this (predict 35-39ms).

#define NPART 32
#define AM 0.95f
#define BM 5.75f
#define AS_ 0.17f
#define BS_ 5.90f

typedef __attribute__((ext_vector_type(8))) short bf16x8;
typedef __attribute__((ext_vector_type(4))) float f32x4;

// 11 physical slots; later lifetimes alias earlier ones (verified disjoint).
enum { iXM = 0, iSQ, iFK, iU2, iU4, iCBA, iCBB, iISQ, iG, iXS, iSBA, NBUF };
#define iV2  iU2
#define iV4  iU4
#define iV3  iCBA
#define iHH  iCBA
#define iV8  iCBB
#define iSBB iISQ
#define iSBC iG
#define iPP  iXS

// Matrices stored as bf16 hi+lo planes (value = hi + lo, ~2^-16 rel err).
// PLAIN accesses: L1-cached (write-through), home-XCD-L2-resident (2.75 MB).
__device__ __align__(16) short gHi[NBUF][65536];
__device__ __align__(16) short gLo[NBUF][65536];
__device__ float g_aS[256][40];   // per-step regrouped Cheb coeffs of x^{t_k}
__device__ float g_aM[12];        // regrouped Cheb coeffs of x^{-1/2}

struct __align__(128) Ctr { int v; int pad[31]; };  // one 128B line per counter
__device__ __align__(128) int g_flags[32];  // per-block generation, ONE line
__device__ Ctr g_slot;            // participant slot allocator
__device__ int g_xcd;             // CAS-elected home XCD (-1 = unset)

__device__ __forceinline__ short f2bf(float x) {
  unsigned u = __builtin_bit_cast(unsigned, x);
  unsigned r = (u + 0x7FFFu + ((u >> 16) & 1u)) >> 16;   // RNE to bf16
  return (short)(unsigned short)r;
}
__device__ __forceinline__ float bf2f(short h) {
  unsigned u = ((unsigned)(unsigned short)h) << 16;
  return __builtin_bit_cast(float, u);
}
__device__ __forceinline__ void wrm(int m, int idx, float v) {
  short h = f2bf(v);
  gHi[m][idx] = h;                       // plain write-through store
  gLo[m][idx] = f2bf(v - bf2f(h));
}

// C(arow, bcol) fragment of A*B; B symmetric -> read B by rows (dwordx4).
// Split hi/lo bf16: 3 MFMAs per K-chunk, ~1e-5 rel err per matmul.
// Plain loads: L1/L2 served, compiler-scheduled (fine-grained waitcnts).
__device__ __forceinline__ f32x4 mmbf(int Ai, int Bi, int arow, int bcol, int kq) {
  f32x4 acc = {0.0f, 0.0f, 0.0f, 0.0f};
  const short* ah = gHi[Ai] + arow * 256 + kq;
  const short* al = gLo[Ai] + arow * 256 + kq;
  const short* bh = gHi[Bi] + bcol * 256 + kq;
  const short* bl = gLo[Bi] + bcol * 256 + kq;
#pragma unroll
  for (int k0 = 0; k0 < 256; k0 += 32) {
    bf16x8 Ah = *(const bf16x8*)(ah + k0);
    bf16x8 Al = *(const bf16x8*)(al + k0);
    bf16x8 Bh = *(const bf16x8*)(bh + k0);
    bf16x8 Bl = *(const bf16x8*)(bl + k0);
    acc = __builtin_amdgcn_mfma_f32_16x16x32_bf16(Ah, Bh, acc, 0, 0, 0);
    acc = __builtin_amdgcn_mfma_f32_16x16x32_bf16(Al, Bh, acc, 0, 0, 0);
    acc = __builtin_amdgcn_mfma_f32_16x16x32_bf16(Ah, Bl, acc, 0, 0, 0);
  }
  return acc;
}

// FLAT grid barrier (single hop).
// Release: each wave drains its write-through data stores (vmcnt 0), then
// __syncthreads (all 8 waves' data in shared home-XCD L2). Wave0/lane0 then
// publishes this block's generation flag with ONE agent-scope store (fire &
// forget; 32 such stores pipeline at the MALL bank - no RMW dependency chain,
// no publish hop). Detection: EVERY wave polls all 32 flags with one vector
// load (lanes 0..31) until __all(flag >= n); then invalidates its own CU L1
// (bare buffer_inv: no sc1 -> L2 untouched, zero traffic). No trailing
// __syncthreads needed: each wave independently observes global completion.
__device__ __forceinline__ void gridbar(int vbid, int lane, int wave, int* pgen) {
  asm volatile("s_waitcnt vmcnt(0) lgkmcnt(0)" ::: "memory");
  __syncthreads();
  const int n = ++(*pgen);
  if (wave == 0 && lane == 0)
    __hip_atomic_store(&g_flags[vbid], n, __ATOMIC_RELAXED,
                       __HIP_MEMORY_SCOPE_AGENT);
  for (;;) {
    int fv = n;
    if (lane < NPART)
      fv = __hip_atomic_load(&g_flags[lane], __ATOMIC_RELAXED,
                             __HIP_MEMORY_SCOPE_AGENT);
    if (__all(fv >= n)) break;
    __builtin_amdgcn_s_sleep(2);
  }
  asm volatile("buffer_inv" ::: "memory");   // L1-only; home L2 holds truth
  __builtin_amdgcn_sched_barrier(0);
}

// Chebyshev-PS regrouping: p = sum_j c_j T_j  ->  sum_i q_i(x) T_i(T_s(x)),
// q_i = sum_r a[i][r] T_r.  a[i][r] = 2c[is+r] - a[i+1][s-r] (a[i][0]=c[is]);
// a[0][r] = c[r] - 0.5 a[1][s-r]; a[0][0] = c[0].
__device__ void regroup_d(const double* c, float* outp, int s, int m) {
  double al[64];
  for (int i = m; i >= 1; i--)
    for (int r = 0; r < s; r++) {
      double v;
      if (r == 0) v = c[s * i];
      else v = 2.0 * c[s * i + r] - ((i == m) ? 0.0 : al[s * (i + 1) + (s - r)]);
      al[s * i + r] = v;
    }
  al[0] = c[0];
  for (int r = 1; r < s; r++) al[r] = c[r] - 0.5 * al[s + (s - r)];
  int tot = s * (m + 1);
  for (int j = 0; j < tot; j++) outp[j] = (float)al[j];
}

// Setup: per-step Chebyshev coefficients (128-node DCT in fp64) + state reset.
__global__ void setup_kernel(const float* __restrict__ wts) {
  const int k = blockIdx.x;
  const int lane = threadIdx.x;
  __shared__ double s_fv[128];
  __shared__ double s_c[64];
  const double PI = 3.14159265358979323846;
  if (k < 256) {
    double w0 = (double)wts[2 * k], w1 = (double)wts[2 * k + 1];
    double t = 1.0 / (1.0 + exp(w0 - w1));     // softmax(...)[:,1]
    double c0 = 0.5 * ((double)AS_ + (double)BS_), h0 = 0.5 * ((double)BS_ - (double)AS_);
    for (int i = lane; i < 128; i += 64) {
      double th = (i + 0.5) * PI / 128.0;
      double y = c0 + h0 * cos(th);
      s_fv[i] = pow(y, t);
    }
    __syncthreads();
    if (lane < 40) {
      double s = 0.0;
      for (int i = 0; i < 128; i++) {
        double th = (i + 0.5) * PI / 128.0;
        s += s_fv[i] * cos((double)lane * th);
      }
      s_c[lane] = s * ((lane == 0) ? 1.0 : 2.0) / 128.0;
    }
    __syncthreads();
    if (lane == 0) regroup_d(s_c, g_aS[k], 8, 4);
  } else {
    double c0 = 0.5 * ((double)AM + (double)BM), h0 = 0.5 * ((double)BM - (double)AM);
    for (int i = lane; i < 128; i += 64) {
      double th = (i + 0.5) * PI / 128.0;
      double y = c0 + h0 * cos(th);
      s_fv[i] = 1.0 / sqrt(y);
    }
    __syncthreads();
    if (lane < 12) {
      double s = 0.0;
      for (int i = 0; i < 128; i++) {
        double th = (i + 0.5) * PI / 128.0;
        s += s_fv[i] * cos((double)lane * th);
      }
      s_c[lane] = s * ((lane == 0) ? 1.0 : 2.0) / 128.0;
    }
    __syncthreads();
    if (lane == 0) {
      regroup_d(s_c, g_aM, 4, 2);
      g_slot.v = 0; g_xcd = -1;
      for (int j = 0; j < 32; j++) g_flags[j] = 0;
    }
  }
}

// 32 participants x 512 thr, 1 block/CU -> spread across the home XCD's 32
// CUs. 256 waves = one 16x16 C-tile per wave.
__global__ void __launch_bounds__(512, 1) frechet_kernel(const float* __restrict__ f,
                                                         float* __restrict__ out) {
  __shared__ int s_vbid;
  int xcc;
  asm volatile("s_getreg_b32 %0, hwreg(HW_REG_XCC_ID)" : "=s"(xcc));
  xcc &= 7;
  if (threadIdx.x == 0) {
    // Elect the home XCD: first block's XCC wins (no hard-coded ID).
    int expected = -1;
    bool won = __hip_atomic_compare_exchange_strong(
        &g_xcd, &expected, xcc, __ATOMIC_RELAXED, __ATOMIC_RELAXED,
        __HIP_MEMORY_SCOPE_AGENT);
    int chosen = won ? xcc : expected;
    int slot = -1;
    if (chosen == xcc)
      slot = __hip_atomic_fetch_add(&g_slot.v, 1, __ATOMIC_RELAXED,
                                    __HIP_MEMORY_SCOPE_AGENT);
    s_vbid = slot;
  }
  __syncthreads();
  const int vbid = s_vbid;
  if (vbid < 0 || vbid >= NPART) return;   // off-home or overflow: exit

  const int tid = threadIdx.x;
  const int lane = tid & 63, wave = tid >> 6;
  const int tr = (vbid >> 2) * 32, tc = (vbid & 3) * 64;  // 8x4 grid of 32x64
  const int sr = (wave >> 2) * 16, sc = (wave & 3) * 16;  // 2x4 waves of 16x16
  const int arow = tr + sr + (lane & 15);     // A-fragment row (global)
  const int colg = tc + sc + (lane & 15);     // C col = B-sym row (global)
  const int kq = (lane >> 4) * 8;             // K sub-offset within chunk
  const int row0 = tr + sr + (lane >> 4) * 4; // C rows for acc[0..3]
  const int fbase = (vbid * 512 + tid) * 4;   // 4 contiguous f elems / thread
  int gen = 0;                                // per-thread barrier generation

  const float sM = 2.0f / (BM - AM), cM = 0.5f * (AM + BM);
  const float sS = 2.0f / (BS_ - AS_), cS = 0.5f * (AS_ + BS_);

  // Register-carried per-thread values (each at idx=(row0+r)*256+colg; every
  // scalar operand below was produced by THIS thread in an earlier round).
  float xmr[4], u2r[4], cbar[4], qm1r[4], qm0r[4], isqr[4];
  float xsr[4], v2r[4], v3r[4], v4r[4];
  float qs3r[4], qs2r[4], qs1r[4], qs0r[4], sbar[4], sbbr[4], sbcr[4];

  // Init: XM = sM*(I - cM*I) at tile positions; stage f_0 into bf16 planes.
  {
    float4 f0 = *(const float4*)(f + fbase);
    float fv[4] = {f0.x, f0.y, f0.z, f0.w};
#pragma unroll
    for (int r = 0; r < 4; r++) {
      int row = row0 + r, idx = row * 256 + colg;
      xmr[r] = (row == colg) ? sM * (1.0f - cM) : 0.0f;
      wrm(iXM, idx, xmr[r]);
      wrm(iFK, fbase + r, fv[r]);
    }
  }
  gridbar(vbid, lane, wave, &gen);

  for (int k = 0; k < 256; k++) {
    const float* aS = g_aS[k];
    const float* aM = g_aM;

    // ---- ISQ = p(M) ~ M^{-1/2}: s=4, m=2, deg 11 ----
    { // r1: U2 = 2*XM*XM - I
      f32x4 a = mmbf(iXM, iXM, arow, colg, kq);
#pragma unroll
      for (int r = 0; r < 4; r++) {
        int row = row0 + r, idx = row * 256 + colg;
        u2r[r] = 2.0f * a[r] - ((row == colg) ? 1.0f : 0.0f);
        wrm(iU2, idx, u2r[r]);
      }
    }
    gridbar(vbid, lane, wave, &gen);
    { // r2: U3 (regs), U4 ; q2 (CBA) global, Q1/Q0 combos register-only
      f32x4 a3 = mmbf(iXM, iU2, arow, colg, kq);
      f32x4 a4 = mmbf(iU2, iU2, arow, colg, kq);
#pragma unroll
      for (int r = 0; r < 4; r++) {
        int row = row0 + r, idx = row * 256 + colg;
        float dI = (row == colg) ? 1.0f : 0.0f;
        float xm = xmr[r], u2 = u2r[r];
        float u3 = 2.0f * a3[r] - xm;
        wrm(iU4, idx, 2.0f * a4[r] - dI);
        cbar[r] = aM[8] * dI + aM[9] * xm + aM[10] * u2 + aM[11] * u3;
        wrm(iCBA, idx, cbar[r]);
        qm1r[r] = aM[4] * dI + aM[5] * xm + aM[6] * u2 + aM[7] * u3;
        qm0r[r] = aM[0] * dI + aM[1] * xm + aM[2] * u2 + aM[3] * u3;
      }
    }
    gridbar(vbid, lane, wave, &gen);
    { // r3: CBB = 2*U4*CBA + Q1
      f32x4 a = mmbf(iU4, iCBA, arow, colg, kq);
#pragma unroll
      for (int r = 0; r < 4; r++) {
        int idx = (row0 + r) * 256 + colg;
        wrm(iCBB, idx, 2.0f * a[r] + qm1r[r]);
      }
    }
    gridbar(vbid, lane, wave, &gen);
    { // r4: ISQ = U4*CBB - CBA + Q0
      f32x4 a = mmbf(iU4, iCBB, arow, colg, kq);
#pragma unroll
      for (int r = 0; r < 4; r++) {
        int idx = (row0 + r) * 256 + colg;
        isqr[r] = a[r] - cbar[r] + qm0r[r];
        wrm(iISQ, idx, isqr[r]);
      }
    }
    gridbar(vbid, lane, wave, &gen);
    { // r5: SQ = (1/sM)*XM*ISQ + cM*ISQ ; G = ISQ*FK
      f32x4 a = mmbf(iXM, iISQ, arow, colg, kq);
      f32x4 b = mmbf(iISQ, iFK, arow, colg, kq);
#pragma unroll
      for (int r = 0; r < 4; r++) {
        int idx = (row0 + r) * 256 + colg;
        wrm(iSQ, idx, a[r] * (1.0f / sM) + cM * isqr[r]);
        wrm(iG, idx, b[r]);
      }
    }
    gridbar(vbid, lane, wave, &gen);
    { // r6: XS = sS*(G*ISQ) - sS*cS*I
      f32x4 a = mmbf(iG, iISQ, arow, colg, kq);
#pragma unroll
      for (int r = 0; r < 4; r++) {
        int row = row0 + r, idx = row * 256 + colg;
        xsr[r] = sS * a[r] - sS * cS * ((row == colg) ? 1.0f : 0.0f);
        wrm(iXS, idx, xsr[r]);
      }
    }
    gridbar(vbid, lane, wave, &gen);

    // ---- P = p(S) ~ S^t: s=8, m=4, deg 39 ----
    { // r7: V2 = 2*XS*XS - I   (V2 aliases U2's slot; U2 dead after r2)
      f32x4 a = mmbf(iXS, iXS, arow, colg, kq);
#pragma unroll
      for (int r = 0; r < 4; r++) {
        int row = row0 + r, idx = row * 256 + colg;
        v2r[r] = 2.0f * a[r] - ((row == colg) ? 1.0f : 0.0f);
        wrm(iV2, idx, v2r[r]);
      }
    }
    gridbar(vbid, lane, wave, &gen);
    { // r8: V3 = 2*XS*V2 - XS ; V4 = 2*V2*V2 - I  (alias CBA / U4 slots)
      f32x4 a = mmbf(iXS, iV2, arow, colg, kq);
      f32x4 b = mmbf(iV2, iV2, arow, colg, kq);
#pragma unroll
      for (int r = 0; r < 4; r++) {
        int row = row0 + r, idx = row * 256 + colg;
        float dI = (row == colg) ? 1.0f : 0.0f;
        v3r[r] = 2.0f * a[r] - xsr[r];
        v4r[r] = 2.0f * b[r] - dI;
        wrm(iV3, idx, v3r[r]);
        wrm(iV4, idx, v4r[r]);
      }
    }
    gridbar(vbid, lane, wave, &gen);
    { // r9: V5..V7 (regs), V8 (alias CBB), q4->SBA; Q3..Q0 regs; f_{k+1}
      f32x4 fq;
      if (k < 255) {
        const f32x4* fp = (const f32x4*)(f + (size_t)(k + 1) * 65536 + fbase);
        fq = __builtin_nontemporal_load(fp);   // don't pollute home-XCD L2
      } else {
        fq = (f32x4){0.f, 0.f, 0.f, 0.f};
      }
      f32x4 a5 = mmbf(iV2, iV3, arow, colg, kq);
      f32x4 a6 = mmbf(iV3, iV3, arow, colg, kq);
      f32x4 a7 = mmbf(iV3, iV4, arow, colg, kq);
      f32x4 a8 = mmbf(iV4, iV4, arow, colg, kq);
#pragma unroll
      for (int r = 0; r < 4; r++) {
        int row = row0 + r, idx = row * 256 + colg;
        float dI = (row == colg) ? 1.0f : 0.0f;
        float xs = xsr[r], v2 = v2r[r], v3 = v3r[r], v4 = v4r[r];
        float v5 = 2.0f * a5[r] - xs;   // T5 = 2*T2*T3 - T1
        float v6 = 2.0f * a6[r] - dI;   // T6 = 2*T3*T3 - T0
        float v7 = 2.0f * a7[r] - xs;   // T7 = 2*T3*T4 - T1
        float v8 = 2.0f * a8[r] - dI;   // T8 = 2*T4*T4 - T0
        wrm(iV8, idx, v8);
        sbar[r] = aS[32] * dI + aS[33] * xs + aS[34] * v2 + aS[35] * v3 +
                  aS[36] * v4 + aS[37] * v5 + aS[38] * v6 + aS[39] * v7;
        wrm(iSBA, idx, sbar[r]);
        qs3r[r] = aS[24] * dI + aS[25] * xs + aS[26] * v2 + aS[27] * v3 +
                  aS[28] * v4 + aS[29] * v5 + aS[30] * v6 + aS[31] * v7;
        qs2r[r] = aS[16] * dI + aS[17] * xs + aS[18] * v2 + aS[19] * v3 +
                  aS[20] * v4 + aS[21] * v5 + aS[22] * v6 + aS[23] * v7;
        qs1r[r] = aS[8] * dI + aS[9] * xs + aS[10] * v2 + aS[11] * v3 +
                  aS[12] * v4 + aS[13] * v5 + aS[14] * v6 + aS[15] * v7;
        qs0r[r] = aS[0] * dI + aS[1] * xs + aS[2] * v2 + aS[3] * v3 +
                  aS[4] * v4 + aS[5] * v5 + aS[6] * v6 + aS[7] * v7;
      }
      if (k < 255) {
        float fv[4] = {fq[0], fq[1], fq[2], fq[3]};
#pragma unroll
        for (int r = 0; r < 4; r++) wrm(iFK, fbase + r, fv[r]);
      }
    }
    gridbar(vbid, lane, wave, &gen);
    { // r10: b3 = 2*V8*b4 + Q3   (SBB aliases ISQ slot; ISQ dead after r6)
      f32x4 a = mmbf(iV8, iSBA, arow, colg, kq);
#pragma unroll
      for (int r = 0; r < 4; r++) {
        int idx = (row0 + r) * 256 + colg;
        sbbr[r] = 2.0f * a[r] + qs3r[r];
        wrm(iSBB, idx, sbbr[r]);
      }
    }
    gridbar(vbid, lane, wave, &gen);
    { // r11: b2 = 2*V8*b3 - b4 + Q2   (SBC aliases G slot; G dead after r6)
      f32x4 a = mmbf(iV8, iSBB, arow, colg, kq);
#pragma unroll
      for (int r = 0; r < 4; r++) {
        int idx = (row0 + r) * 256 + colg;
        sbcr[r] = 2.0f * a[r] - sbar[r] + qs2r[r];
        wrm(iSBC, idx, sbcr[r]);
      }
    }
    gridbar(vbid, lane, wave, &gen);
    { // r12: b1 = 2*V8*b2 - b3 + Q1  (rewrites SBA slot; b4 dead after r11)
      f32x4 a = mmbf(iV8, iSBC, arow, colg, kq);
#pragma unroll
      for (int r = 0; r < 4; r++) {
        int idx = (row0 + r) * 256 + colg;
        wrm(iSBA, idx, 2.0f * a[r] - sbbr[r] + qs1r[r]);
      }
    }
    gridbar(vbid, lane, wave, &gen);
    { // r13: P = V8*b1 - b2 + Q0   (PP aliases XS slot; XS dead after r8)
      f32x4 a = mmbf(iV8, iSBA, arow, colg, kq);
#pragma unroll
      for (int r = 0; r < 4; r++) {
        int idx = (row0 + r) * 256 + colg;
        wrm(iPP, idx, a[r] - sbcr[r] + qs0r[r]);
      }
    }
    gridbar(vbid, lane, wave, &gen);
    { // r14: HH = SQ*P   (HH aliases V3/CBA slot; V3 dead after r9)
      f32x4 a = mmbf(iSQ, iPP, arow, colg, kq);
#pragma unroll
      for (int r = 0; r < 4; r++) {
        int idx = (row0 + r) * 256 + colg;
        wrm(iHH, idx, a[r]);
      }
    }
    gridbar(vbid, lane, wave, &gen);
    { // r15: Mn = HH*SQ -> out[k] (fp32, NT); XM_next = sM*(Mn - cM*I)
      f32x4 a = mmbf(iHH, iSQ, arow, colg, kq);
      float* ok = out + (size_t)k * 65536;
#pragma unroll
      for (int r = 0; r < 4; r++) {
        int row = row0 + r, idx = row * 256 + colg;
        float dI = (row == colg) ? 1.0f : 0.0f;
        float v = a[r];
        __builtin_nontemporal_store(v, ok + idx);
        xmr[r] = sM * (v - cM * dI);
        wrm(iXM, idx, xmr[r]);
      }
    }
    gridbar(vbid, lane, wave, &gen);
  }
}

extern "C" void kernel_launch(void* const* d_in, const int* in_sizes, int n_in,
                              void* d_out, int out_size, void* d_ws, size_t ws_size,
                              hipStream_t stream) {
  (void)in_sizes; (void)n_in; (void)d_ws; (void)ws_size; (void)out_size;
  const float* f = (const float*)d_in[0];
  const float* w = (const float*)d_in[1];
  float* out = (float*)d_out;

  setup_kernel<<<dim3(257), dim3(64), 0, stream>>>(w);

  // 1024 probe blocks; the first block CAS-elects its XCD as "home"; the
  // first NPART=32 blocks landing on the home XCD participate (1 block/CU ->
  // spread over its 32 CUs); all others exit instantly. The barrier uses
  // agent-scope flag stores/loads, so a broken placement produces wrong data
  // (visible), never a hang.
  frechet_kernel<<<dim3(1024), dim3(512), 0, stream>>>(f, out);
}

// Round 9
// 44109.335 us; speedup vs baseline: 1.0237x; 1.0237x over previous
//
#include <hip/hip_runtime.h>
#include <math.h>

// BatchFrechetMean: inductive geodesic mean of 256 SPD 256x256 matrices.
// Eigh-free Chebyshev evaluation of M^{-1/2} and S^t, persistent SINGLE-XCD
// kernel, PLAIN-CACHED data plane (R9, verified) + L2-LOCAL FLAG BARRIER.
//
// R11b: R11 resubmit (R8 bench died on infra: "container failed twice", same
// string as Round 0 which later benched fine) + one robustness fix: arrival
// now mirrors the generation into an AGENT-scope store too, so the MALL
// fallback poll can always observe it (a plain store may sit dirty in the
// home L2, invisible to MALL loads if placement ever broke). Fire-and-forget,
// off the critical path (R10 measured arrival stores as perf-neutral).
//
// Theory (R11): R10 (flag barrier via MALL) was NEUTRAL vs R9 (RMW barrier
// via MALL): 45.2 vs 44.9ms => arrival mechanics don't matter; the common
// term is agent(MALL)-scope store->load visibility on the critical path
// (~6-8us of 11.7us/round). Fix: sync through the SAME shared home-XCD L2
// the data plane uses (R9-proven visible cross-CU): arrival = plain volatile
// store of the generation (write-through ~200cy); detection = wave 0 polls
// {buffer_inv (L1-only); plain vector load of all 32 flags} at L2-hit
// latency while waves 1..7 park at s_barrier (no loads while parked -> no
// stale L1; per-wave post-inv deleted). NO MALL op on the k-loop critical
// path. Hang-proofing: after 8192 failed polls fall back to agent-scope
// loads (sees the mirrored agent store).
//
// Measured HW facts (this session):
//  - sc0/sc1 data accesses are MALL-serviced on gfx950, NOT L2-allocating
//    (R7/R8c: FETCH ~= full operand stream).
//  - Plain write-through stores ARE visible to sibling CUs via the shared
//    home-XCD L2 (R9 passes with FETCH 2.0GB << operand stream).
//  - XCC election + single-XCD placement works (R9/R10 correctness).
//  - Barrier arrival mechanics (RMW chain vs flag stores) are perf-neutral.
//
// Spectral bounds (provable): lambda(f) in [1, ~5.2] => lambda(M) in [1, 5.5],
// lambda(S) in [1/5.75, 5.75]. Approximation intervals with margin:
//   x^{-1/2} on [0.95, 5.75], deg 11 (s=4, m=2)  -> err ~3e-5
//   x^{t}    on [0.17, 5.90], deg 39 (s=8, m=4)  -> err ~1e-6
//
// Perf history: R5 41.1ms -> R6 102.5 -> R7 51 -> R8c 72 -> R9 44.9 ->
// R10 45.2 (neutral) -> R11b this (predict 18-28ms; if neutral, next round =
// barrier ablation probe).

#define NPART 32
#define AM 0.95f
#define BM 5.75f
#define AS_ 0.17f
#define BS_ 5.90f

typedef __attribute__((ext_vector_type(8))) short bf16x8;
typedef __attribute__((ext_vector_type(4))) float f32x4;

// 11 physical slots; later lifetimes alias earlier ones (verified disjoint).
enum { iXM = 0, iSQ, iFK, iU2, iU4, iCBA, iCBB, iISQ, iG, iXS, iSBA, NBUF };
#define iV2  iU2
#define iV4  iU4
#define iV3  iCBA
#define iHH  iCBA
#define iV8  iCBB
#define iSBB iISQ
#define iSBC iG
#define iPP  iXS

// Matrices stored as bf16 hi+lo planes (value = hi + lo, ~2^-16 rel err).
// PLAIN accesses: L1-cached (write-through), home-XCD-L2-resident (2.75 MB).
__device__ __align__(16) short gHi[NBUF][65536];
__device__ __align__(16) short gLo[NBUF][65536];
__device__ float g_aS[256][40];   // per-step regrouped Cheb coeffs of x^{t_k}
__device__ float g_aM[12];        // regrouped Cheb coeffs of x^{-1/2}

struct __align__(128) Ctr { int v; int pad[31]; };  // one 128B line per counter
__device__ __align__(128) int g_flags[32];   // L2-poll flags, ONE 128B line
__device__ __align__(128) int g_flagsA[32];  // MALL-mirror flags (fallback)
__device__ Ctr g_slot;            // participant slot allocator
__device__ int g_xcd;             // CAS-elected home XCD (-1 = unset)

__device__ __forceinline__ short f2bf(float x) {
  unsigned u = __builtin_bit_cast(unsigned, x);
  unsigned r = (u + 0x7FFFu + ((u >> 16) & 1u)) >> 16;   // RNE to bf16
  return (short)(unsigned short)r;
}
__device__ __forceinline__ float bf2f(short h) {
  unsigned u = ((unsigned)(unsigned short)h) << 16;
  return __builtin_bit_cast(float, u);
}
__device__ __forceinline__ void wrm(int m, int idx, float v) {
  short h = f2bf(v);
  gHi[m][idx] = h;                       // plain write-through store
  gLo[m][idx] = f2bf(v - bf2f(h));
}

// C(arow, bcol) fragment of A*B; B symmetric -> read B by rows (dwordx4).
// Split hi/lo bf16: 3 MFMAs per K-chunk, ~1e-5 rel err per matmul.
// Plain loads: L1/L2 served, compiler-scheduled (fine-grained waitcnts).
__device__ __forceinline__ f32x4 mmbf(int Ai, int Bi, int arow, int bcol, int kq) {
  f32x4 acc = {0.0f, 0.0f, 0.0f, 0.0f};
  const short* ah = gHi[Ai] + arow * 256 + kq;
  const short* al = gLo[Ai] + arow * 256 + kq;
  const short* bh = gHi[Bi] + bcol * 256 + kq;
  const short* bl = gLo[Bi] + bcol * 256 + kq;
#pragma unroll
  for (int k0 = 0; k0 < 256; k0 += 32) {
    bf16x8 Ah = *(const bf16x8*)(ah + k0);
    bf16x8 Al = *(const bf16x8*)(al + k0);
    bf16x8 Bh = *(const bf16x8*)(bh + k0);
    bf16x8 Bl = *(const bf16x8*)(bl + k0);
    acc = __builtin_amdgcn_mfma_f32_16x16x32_bf16(Ah, Bh, acc, 0, 0, 0);
    acc = __builtin_amdgcn_mfma_f32_16x16x32_bf16(Al, Bh, acc, 0, 0, 0);
    acc = __builtin_amdgcn_mfma_f32_16x16x32_bf16(Ah, Bl, acc, 0, 0, 0);
  }
  return acc;
}

// L2-LOCAL grid barrier.
// Release: each wave drains its write-through data stores (vmcnt 0), then
// __syncthreads -> all 8 waves' data in shared home-XCD L2. Wave0/lane0
// publishes the block generation with a PLAIN volatile store (write-through,
// ~200cy to L2) AND an agent-scope mirror store (fire-and-forget; only read
// by the fallback path). Detection: wave 0 alone polls {buffer_inv (L1-only,
// no traffic); plain vector load of all 32 flags}; waves 1..7 park at the
// trailing s_barrier, issuing no loads meanwhile -> no stale L1 lines.
// Hang-proofing: after 8192 failed polls, poll the MALL mirror instead.
__device__ __forceinline__ void gridbar(int vbid, int lane, int wave, int* pgen) {
  asm volatile("s_waitcnt vmcnt(0) lgkmcnt(0)" ::: "memory");
  __syncthreads();
  const int n = ++(*pgen);
  if (wave == 0) {
    if (lane == 0) {
      volatile int* fp = (volatile int*)&g_flags[vbid];
      *fp = n;                          // plain write-through -> home L2
      __hip_atomic_store(&g_flagsA[vbid], n, __ATOMIC_RELAXED,
                         __HIP_MEMORY_SCOPE_AGENT);   // MALL mirror
    }
    int iter = 0;
    for (;;) {
      asm volatile("buffer_inv" ::: "memory");   // L1-only; L2 holds truth
      int fv = n;
      if (lane < NPART) {
        if (iter < 8192) {
          volatile int* fp = (volatile int*)&g_flags[lane];
          fv = *fp;                     // L2-hit poll (~200-400cy)
        } else {
          fv = __hip_atomic_load(&g_flagsA[lane], __ATOMIC_RELAXED,
                                 __HIP_MEMORY_SCOPE_AGENT);  // MALL fallback
        }
      }
      if (__all(fv >= n)) break;
      ++iter;
      __builtin_amdgcn_s_sleep(1);
    }
  }
  __syncthreads();   // releases waves 1..7; L1 fresh (see note above)
  __builtin_amdgcn_sched_barrier(0);
}

// Chebyshev-PS regrouping: p = sum_j c_j T_j  ->  sum_i q_i(x) T_i(T_s(x)),
// q_i = sum_r a[i][r] T_r.  a[i][r] = 2c[is+r] - a[i+1][s-r] (a[i][0]=c[is]);
// a[0][r] = c[r] - 0.5 a[1][s-r]; a[0][0] = c[0].
__device__ void regroup_d(const double* c, float* outp, int s, int m) {
  double al[64];
  for (int i = m; i >= 1; i--)
    for (int r = 0; r < s; r++) {
      double v;
      if (r == 0) v = c[s * i];
      else v = 2.0 * c[s * i + r] - ((i == m) ? 0.0 : al[s * (i + 1) + (s - r)]);
      al[s * i + r] = v;
    }
  al[0] = c[0];
  for (int r = 1; r < s; r++) al[r] = c[r] - 0.5 * al[s + (s - r)];
  int tot = s * (m + 1);
  for (int j = 0; j < tot; j++) outp[j] = (float)al[j];
}

// Setup: per-step Chebyshev coefficients (128-node DCT in fp64) + state reset.
__global__ void setup_kernel(const float* __restrict__ wts) {
  const int k = blockIdx.x;
  const int lane = threadIdx.x;
  __shared__ double s_fv[128];
  __shared__ double s_c[64];
  const double PI = 3.14159265358979323846;
  if (k < 256) {
    double w0 = (double)wts[2 * k], w1 = (double)wts[2 * k + 1];
    double t = 1.0 / (1.0 + exp(w0 - w1));     // softmax(...)[:,1]
    double c0 = 0.5 * ((double)AS_ + (double)BS_), h0 = 0.5 * ((double)BS_ - (double)AS_);
    for (int i = lane; i < 128; i += 64) {
      double th = (i + 0.5) * PI / 128.0;
      double y = c0 + h0 * cos(th);
      s_fv[i] = pow(y, t);
    }
    __syncthreads();
    if (lane < 40) {
      double s = 0.0;
      for (int i = 0; i < 128; i++) {
        double th = (i + 0.5) * PI / 128.0;
        s += s_fv[i] * cos((double)lane * th);
      }
      s_c[lane] = s * ((lane == 0) ? 1.0 : 2.0) / 128.0;
    }
    __syncthreads();
    if (lane == 0) regroup_d(s_c, g_aS[k], 8, 4);
  } else {
    double c0 = 0.5 * ((double)AM + (double)BM), h0 = 0.5 * ((double)BM - (double)AM);
    for (int i = lane; i < 128; i += 64) {
      double th = (i + 0.5) * PI / 128.0;
      double y = c0 + h0 * cos(th);
      s_fv[i] = 1.0 / sqrt(y);
    }
    __syncthreads();
    if (lane < 12) {
      double s = 0.0;
      for (int i = 0; i < 128; i++) {
        double th = (i + 0.5) * PI / 128.0;
        s += s_fv[i] * cos((double)lane * th);
      }
      s_c[lane] = s * ((lane == 0) ? 1.0 : 2.0) / 128.0;
    }
    __syncthreads();
    if (lane == 0) {
      regroup_d(s_c, g_aM, 4, 2);
      g_slot.v = 0; g_xcd = -1;
      for (int j = 0; j < 32; j++) { g_flags[j] = 0; g_flagsA[j] = 0; }
    }
  }
}

// 32 participants x 512 thr, 1 block/CU -> spread across the home XCD's 32
// CUs. 256 waves = one 16x16 C-tile per wave.
__global__ void __launch_bounds__(512, 1) frechet_kernel(const float* __restrict__ f,
                                                         float* __restrict__ out) {
  __shared__ int s_vbid;
  int xcc;
  asm volatile("s_getreg_b32 %0, hwreg(HW_REG_XCC_ID)" : "=s"(xcc));
  xcc &= 7;
  if (threadIdx.x == 0) {
    // Elect the home XCD: first block's XCC wins (no hard-coded ID).
    int expected = -1;
    bool won = __hip_atomic_compare_exchange_strong(
        &g_xcd, &expected, xcc, __ATOMIC_RELAXED, __ATOMIC_RELAXED,
        __HIP_MEMORY_SCOPE_AGENT);
    int chosen = won ? xcc : expected;
    int slot = -1;
    if (chosen == xcc)
      slot = __hip_atomic_fetch_add(&g_slot.v, 1, __ATOMIC_RELAXED,
                                    __HIP_MEMORY_SCOPE_AGENT);
    s_vbid = slot;
  }
  __syncthreads();
  const int vbid = s_vbid;
  if (vbid < 0 || vbid >= NPART) return;   // off-home or overflow: exit

  const int tid = threadIdx.x;
  const int lane = tid & 63, wave = tid >> 6;
  const int tr = (vbid >> 2) * 32, tc = (vbid & 3) * 64;  // 8x4 grid of 32x64
  const int sr = (wave >> 2) * 16, sc = (wave & 3) * 16;  // 2x4 waves of 16x16
  const int arow = tr + sr + (lane & 15);     // A-fragment row (global)
  const int colg = tc + sc + (lane & 15);     // C col = B-sym row (global)
  const int kq = (lane >> 4) * 8;             // K sub-offset within chunk
  const int row0 = tr + sr + (lane >> 4) * 4; // C rows for acc[0..3]
  const int fbase = (vbid * 512 + tid) * 4;   // 4 contiguous f elems / thread
  int gen = 0;                                // per-thread barrier generation

  const float sM = 2.0f / (BM - AM), cM = 0.5f * (AM + BM);
  const float sS = 2.0f / (BS_ - AS_), cS = 0.5f * (AS_ + BS_);

  // Register-carried per-thread values (each at idx=(row0+r)*256+colg; every
  // scalar operand below was produced by THIS thread in an earlier round).
  float xmr[4], u2r[4], cbar[4], qm1r[4], qm0r[4], isqr[4];
  float xsr[4], v2r[4], v3r[4], v4r[4];
  float qs3r[4], qs2r[4], qs1r[4], qs0r[4], sbar[4], sbbr[4], sbcr[4];

  // Init: XM = sM*(I - cM*I) at tile positions; stage f_0 into bf16 planes.
  {
    float4 f0 = *(const float4*)(f + fbase);
    float fv[4] = {f0.x, f0.y, f0.z, f0.w};
#pragma unroll
    for (int r = 0; r < 4; r++) {
      int row = row0 + r, idx = row * 256 + colg;
      xmr[r] = (row == colg) ? sM * (1.0f - cM) : 0.0f;
      wrm(iXM, idx, xmr[r]);
      wrm(iFK, fbase + r, fv[r]);
    }
  }
  gridbar(vbid, lane, wave, &gen);

  for (int k = 0; k < 256; k++) {
    const float* aS = g_aS[k];
    const float* aM = g_aM;

    // ---- ISQ = p(M) ~ M^{-1/2}: s=4, m=2, deg 11 ----
    { // r1: U2 = 2*XM*XM - I
      f32x4 a = mmbf(iXM, iXM, arow, colg, kq);
#pragma unroll
      for (int r = 0; r < 4; r++) {
        int row = row0 + r, idx = row * 256 + colg;
        u2r[r] = 2.0f * a[r] - ((row == colg) ? 1.0f : 0.0f);
        wrm(iU2, idx, u2r[r]);
      }
    }
    gridbar(vbid, lane, wave, &gen);
    { // r2: U3 (regs), U4 ; q2 (CBA) global, Q1/Q0 combos register-only
      f32x4 a3 = mmbf(iXM, iU2, arow, colg, kq);
      f32x4 a4 = mmbf(iU2, iU2, arow, colg, kq);
#pragma unroll
      for (int r = 0; r < 4; r++) {
        int row = row0 + r, idx = row * 256 + colg;
        float dI = (row == colg) ? 1.0f : 0.0f;
        float xm = xmr[r], u2 = u2r[r];
        float u3 = 2.0f * a3[r] - xm;
        wrm(iU4, idx, 2.0f * a4[r] - dI);
        cbar[r] = aM[8] * dI + aM[9] * xm + aM[10] * u2 + aM[11] * u3;
        wrm(iCBA, idx, cbar[r]);
        qm1r[r] = aM[4] * dI + aM[5] * xm + aM[6] * u2 + aM[7] * u3;
        qm0r[r] = aM[0] * dI + aM[1] * xm + aM[2] * u2 + aM[3] * u3;
      }
    }
    gridbar(vbid, lane, wave, &gen);
    { // r3: CBB = 2*U4*CBA + Q1
      f32x4 a = mmbf(iU4, iCBA, arow, colg, kq);
#pragma unroll
      for (int r = 0; r < 4; r++) {
        int idx = (row0 + r) * 256 + colg;
        wrm(iCBB, idx, 2.0f * a[r] + qm1r[r]);
      }
    }
    gridbar(vbid, lane, wave, &gen);
    { // r4: ISQ = U4*CBB - CBA + Q0
      f32x4 a = mmbf(iU4, iCBB, arow, colg, kq);
#pragma unroll
      for (int r = 0; r < 4; r++) {
        int idx = (row0 + r) * 256 + colg;
        isqr[r] = a[r] - cbar[r] + qm0r[r];
        wrm(iISQ, idx, isqr[r]);
      }
    }
    gridbar(vbid, lane, wave, &gen);
    { // r5: SQ = (1/sM)*XM*ISQ + cM*ISQ ; G = ISQ*FK
      f32x4 a = mmbf(iXM, iISQ, arow, colg, kq);
      f32x4 b = mmbf(iISQ, iFK, arow, colg, kq);
#pragma unroll
      for (int r = 0; r < 4; r++) {
        int idx = (row0 + r) * 256 + colg;
        wrm(iSQ, idx, a[r] * (1.0f / sM) + cM * isqr[r]);
        wrm(iG, idx, b[r]);
      }
    }
    gridbar(vbid, lane, wave, &gen);
    { // r6: XS = sS*(G*ISQ) - sS*cS*I
      f32x4 a = mmbf(iG, iISQ, arow, colg, kq);
#pragma unroll
      for (int r = 0; r < 4; r++) {
        int row = row0 + r, idx = row * 256 + colg;
        xsr[r] = sS * a[r] - sS * cS * ((row == colg) ? 1.0f : 0.0f);
        wrm(iXS, idx, xsr[r]);
      }
    }
    gridbar(vbid, lane, wave, &gen);

    // ---- P = p(S) ~ S^t: s=8, m=4, deg 39 ----
    { // r7: V2 = 2*XS*XS - I   (V2 aliases U2's slot; U2 dead after r2)
      f32x4 a = mmbf(iXS, iXS, arow, colg, kq);
#pragma unroll
      for (int r = 0; r < 4; r++) {
        int row = row0 + r, idx = row * 256 + colg;
        v2r[r] = 2.0f * a[r] - ((row == colg) ? 1.0f : 0.0f);
        wrm(iV2, idx, v2r[r]);
      }
    }
    gridbar(vbid, lane, wave, &gen);
    { // r8: V3 = 2*XS*V2 - XS ; V4 = 2*V2*V2 - I  (alias CBA / U4 slots)
      f32x4 a = mmbf(iXS, iV2, arow, colg, kq);
      f32x4 b = mmbf(iV2, iV2, arow, colg, kq);
#pragma unroll
      for (int r = 0; r < 4; r++) {
        int row = row0 + r, idx = row * 256 + colg;
        float dI = (row == colg) ? 1.0f : 0.0f;
        v3r[r] = 2.0f * a[r] - xsr[r];
        v4r[r] = 2.0f * b[r] - dI;
        wrm(iV3, idx, v3r[r]);
        wrm(iV4, idx, v4r[r]);
      }
    }
    gridbar(vbid, lane, wave, &gen);
    { // r9: V5..V7 (regs), V8 (alias CBB), q4->SBA; Q3..Q0 regs; f_{k+1}
      f32x4 fq;
      if (k < 255) {
        const f32x4* fp = (const f32x4*)(f + (size_t)(k + 1) * 65536 + fbase);
        fq = __builtin_nontemporal_load(fp);   // don't pollute home-XCD L2
      } else {
        fq = (f32x4){0.f, 0.f, 0.f, 0.f};
      }
      f32x4 a5 = mmbf(iV2, iV3, arow, colg, kq);
      f32x4 a6 = mmbf(iV3, iV3, arow, colg, kq);
      f32x4 a7 = mmbf(iV3, iV4, arow, colg, kq);
      f32x4 a8 = mmbf(iV4, iV4, arow, colg, kq);
#pragma unroll
      for (int r = 0; r < 4; r++) {
        int row = row0 + r, idx = row * 256 + colg;
        float dI = (row == colg) ? 1.0f : 0.0f;
        float xs = xsr[r], v2 = v2r[r], v3 = v3r[r], v4 = v4r[r];
        float v5 = 2.0f * a5[r] - xs;   // T5 = 2*T2*T3 - T1
        float v6 = 2.0f * a6[r] - dI;   // T6 = 2*T3*T3 - T0
        float v7 = 2.0f * a7[r] - xs;   // T7 = 2*T3*T4 - T1
        float v8 = 2.0f * a8[r] - dI;   // T8 = 2*T4*T4 - T0
        wrm(iV8, idx, v8);
        sbar[r] = aS[32] * dI + aS[33] * xs + aS[34] * v2 + aS[35] * v3 +
                  aS[36] * v4 + aS[37] * v5 + aS[38] * v6 + aS[39] * v7;
        wrm(iSBA, idx, sbar[r]);
        qs3r[r] = aS[24] * dI + aS[25] * xs + aS[26] * v2 + aS[27] * v3 +
                  aS[28] * v4 + aS[29] * v5 + aS[30] * v6 + aS[31] * v7;
        qs2r[r] = aS[16] * dI + aS[17] * xs + aS[18] * v2 + aS[19] * v3 +
                  aS[20] * v4 + aS[21] * v5 + aS[22] * v6 + aS[23] * v7;
        qs1r[r] = aS[8] * dI + aS[9] * xs + aS[10] * v2 + aS[11] * v3 +
                  aS[12] * v4 + aS[13] * v5 + aS[14] * v6 + aS[15] * v7;
        qs0r[r] = aS[0] * dI + aS[1] * xs + aS[2] * v2 + aS[3] * v3 +
                  aS[4] * v4 + aS[5] * v5 + aS[6] * v6 + aS[7] * v7;
      }
      if (k < 255) {
        float fv[4] = {fq[0], fq[1], fq[2], fq[3]};
#pragma unroll
        for (int r = 0; r < 4; r++) wrm(iFK, fbase + r, fv[r]);
      }
    }
    gridbar(vbid, lane, wave, &gen);
    { // r10: b3 = 2*V8*b4 + Q3   (SBB aliases ISQ slot; ISQ dead after r6)
      f32x4 a = mmbf(iV8, iSBA, arow, colg, kq);
#pragma unroll
      for (int r = 0; r < 4; r++) {
        int idx = (row0 + r) * 256 + colg;
        sbbr[r] = 2.0f * a[r] + qs3r[r];
        wrm(iSBB, idx, sbbr[r]);
      }
    }
    gridbar(vbid, lane, wave, &gen);
    { // r11: b2 = 2*V8*b3 - b4 + Q2   (SBC aliases G slot; G dead after r6)
      f32x4 a = mmbf(iV8, iSBB, arow, colg, kq);
#pragma unroll
      for (int r = 0; r < 4; r++) {
        int idx = (row0 + r) * 256 + colg;
        sbcr[r] = 2.0f * a[r] - sbar[r] + qs2r[r];
        wrm(iSBC, idx, sbcr[r]);
      }
    }
    gridbar(vbid, lane, wave, &gen);
    { // r12: b1 = 2*V8*b2 - b3 + Q1  (rewrites SBA slot; b4 dead after r11)
      f32x4 a = mmbf(iV8, iSBC, arow, colg, kq);
#pragma unroll
      for (int r = 0; r < 4; r++) {
        int idx = (row0 + r) * 256 + colg;
        wrm(iSBA, idx, 2.0f * a[r] - sbbr[r] + qs1r[r]);
      }
    }
    gridbar(vbid, lane, wave, &gen);
    { // r13: P = V8*b1 - b2 + Q0   (PP aliases XS slot; XS dead after r8)
      f32x4 a = mmbf(iV8, iSBA, arow, colg, kq);
#pragma unroll
      for (int r = 0; r < 4; r++) {
        int idx = (row0 + r) * 256 + colg;
        wrm(iPP, idx, a[r] - sbcr[r] + qs0r[r]);
      }
    }
    gridbar(vbid, lane, wave, &gen);
    { // r14: HH = SQ*P   (HH aliases V3/CBA slot; V3 dead after r9)
      f32x4 a = mmbf(iSQ, iPP, arow, colg, kq);
#pragma unroll
      for (int r = 0; r < 4; r++) {
        int idx = (row0 + r) * 256 + colg;
        wrm(iHH, idx, a[r]);
      }
    }
    gridbar(vbid, lane, wave, &gen);
    { // r15: Mn = HH*SQ -> out[k] (fp32, NT); XM_next = sM*(Mn - cM*I)
      f32x4 a = mmbf(iHH, iSQ, arow, colg, kq);
      float* ok = out + (size_t)k * 65536;
#pragma unroll
      for (int r = 0; r < 4; r++) {
        int row = row0 + r, idx = row * 256 + colg;
        float dI = (row == colg) ? 1.0f : 0.0f;
        float v = a[r];
        __builtin_nontemporal_store(v, ok + idx);
        xmr[r] = sM * (v - cM * dI);
        wrm(iXM, idx, xmr[r]);
      }
    }
    gridbar(vbid, lane, wave, &gen);
  }
}

extern "C" void kernel_launch(void* const* d_in, const int* in_sizes, int n_in,
                              void* d_out, int out_size, void* d_ws, size_t ws_size,
                              hipStream_t stream) {
  (void)in_sizes; (void)n_in; (void)d_ws; (void)ws_size; (void)out_size;
  const float* f = (const float*)d_in[0];
  const float* w = (const float*)d_in[1];
  float* out = (float*)d_out;

  setup_kernel<<<dim3(257), dim3(64), 0, stream>>>(w);

  // 1024 probe blocks; the first block CAS-elects its XCD as "home"; the
  // first NPART=32 blocks landing on the home XCD participate (1 block/CU ->
  // spread over its 32 CUs); all others exit instantly. The barrier flags
  // live in the shared home-XCD L2 with a MALL-mirrored fallback, so a broken
  // placement produces wrong data (visible), never a hang.
  frechet_kernel<<<dim3(1024), dim3(512), 0, stream>>>(f, out);
}

// Round 10
// 23616.611 us; speedup vs baseline: 1.9121x; 1.8677x over previous
//
#include <hip/hip_runtime.h>
#include <math.h>

// BatchFrechetMean: inductive geodesic mean of 256 SPD 256x256 matrices.
// Eigh-free Chebyshev evaluation of M^{-1/2} and S^t, persistent SINGLE-XCD
// kernel, L2-resident data plane + LDS-STAGED operands (new) + L2 flag barrier.
//
// R12. Post-mortem chain: R9/R10/R11b = 44-45ms across THREE different
// barrier mechanisms => barrier is NOT the cost. The 11.5us/round is the
// data phase, and it is MLP-bound, not BW-bound: per-wave operand streams
// keep only ~8-16 x 16B loads in flight (VGPR=128), 8 waves/CU -> ~2-4KB
// in flight vs ~200-400cy L2 latency -> ~10-20 GB/s/CU -> ~256KB of
// (redundant per-wave) requests/round = ~10-12us. Matches measurement.
// Fix: cooperative LDS staging. Each round stages A-tile (32 rows, 32KB)
// and B-tile (64 rows, 64KB) hi+lo from L2 into LDS with independent
// coalesced 16B loads (512 thr x 4-8 each -> L2-BW-bound ~0.8us/phase),
// then MFMAs read ds_read_b128 (~60cy). XOR swizzle ((row&7)<<4 bytes) on
// BOTH ds-write and ds-read sides kills the 32-way bank conflict of
// row-major 512B rows (G4; rule-21-safe since staging is ds_write, not
// global_load_lds). Cross-round LDS reuse: A1 holds XM (r1-r5), U4 (r3-r4),
// V8 (r10-r13); B holds ISQ across r5->r6. ~1.25MB staged/block/step.
// 128KB static LDS -> 1 block/CU. Barrier/election/math = R11b verbatim.
//
// Measured HW facts (this session): sc-bit accesses are MALL-serviced (no
// L2 alloc); plain write-through stores are cross-CU visible via home-XCD
// L2; XCC election works; barrier mechanics are perf-neutral.
//
// Spectral bounds (provable): lambda(f) in [1, ~5.2] => lambda(M) in [1, 5.5],
// lambda(S) in [1/5.75, 5.75]. Approximation intervals with margin:
//   x^{-1/2} on [0.95, 5.75], deg 11 (s=4, m=2)  -> err ~3e-5
//   x^{t}    on [0.17, 5.90], deg 39 (s=8, m=4)  -> err ~1e-6
//
// Perf history: R5 41.1 -> R6 102.5 -> R7 51 -> R8c 72 -> R9 44.9 ->
// R10 45.2 -> R11b 44.1 -> R12 this (predict 15-25ms).

#define NPART 32
#define AM 0.95f
#define BM 5.75f
#define AS_ 0.17f
#define BS_ 5.90f

typedef __attribute__((ext_vector_type(8))) short bf16x8;
typedef __attribute__((ext_vector_type(4))) float f32x4;

// 11 physical slots; later lifetimes alias earlier ones (verified disjoint).
enum { iXM = 0, iSQ, iFK, iU2, iU4, iCBA, iCBB, iISQ, iG, iXS, iSBA, NBUF };
#define iV2  iU2
#define iV4  iU4
#define iV3  iCBA
#define iHH  iCBA
#define iV8  iCBB
#define iSBB iISQ
#define iSBC iG
#define iPP  iXS

// LDS regions (shorts). B: 64 rows (hi 16384 + lo 16384). A1/A2: 32 rows each.
#define LDS_B   0
#define LDS_A1  32768
#define LDS_A2  49152

// Matrices stored as bf16 hi+lo planes (value = hi + lo, ~2^-16 rel err).
// PLAIN accesses: home-XCD-L2-resident (2.75 MB).
__device__ __align__(16) short gHi[NBUF][65536];
__device__ __align__(16) short gLo[NBUF][65536];
__device__ float g_aS[256][40];   // per-step regrouped Cheb coeffs of x^{t_k}
__device__ float g_aM[12];        // regrouped Cheb coeffs of x^{-1/2}

struct __align__(128) Ctr { int v; int pad[31]; };
__device__ __align__(128) int g_flags[32];   // L2-poll flags, ONE 128B line
__device__ __align__(128) int g_flagsA[32];  // MALL-mirror flags (fallback)
__device__ Ctr g_slot;            // participant slot allocator
__device__ int g_xcd;             // CAS-elected home XCD (-1 = unset)

__device__ __forceinline__ short f2bf(float x) {
  unsigned u = __builtin_bit_cast(unsigned, x);
  unsigned r = (u + 0x7FFFu + ((u >> 16) & 1u)) >> 16;   // RNE to bf16
  return (short)(unsigned short)r;
}
__device__ __forceinline__ float bf2f(short h) {
  unsigned u = ((unsigned)(unsigned short)h) << 16;
  return __builtin_bit_cast(float, u);
}
__device__ __forceinline__ void wrm(int m, int idx, float v) {
  short h = f2bf(v);
  gHi[m][idx] = h;                       // plain write-through store
  gLo[m][idx] = f2bf(v - bf2f(h));
}

// Cooperative stage: nrows rows of gHi/gLo[m] starting at grow0 -> LDS at
// soff (hi), soff+nrows*256 (lo). Coalesced 16B loads, all independent ->
// L2-BW-bound. Swizzle: short-index c ^= ((r&7)<<3) (== byte<<4), 16B-safe.
__device__ __forceinline__ void stage(short* slds, int m, int grow0, int nrows,
                                      int soff, int tid) {
  const int nch = nrows * 32;            // 16B chunks per plane
  const int loSh = nrows * 256;
#pragma unroll 2
  for (int q = tid; q < nch; q += 512) {
    int r = q >> 5, c16 = q & 31;
    int gidx = (grow0 + r) * 256 + c16 * 8;
    bf16x8 hv = *(const bf16x8*)(gHi[m] + gidx);
    bf16x8 lv = *(const bf16x8*)(gLo[m] + gidx);
    int sidx = soff + r * 256 + ((c16 * 8) ^ ((r & 7) << 3));
    *(bf16x8*)(slds + sidx) = hv;
    *(bf16x8*)(slds + sidx + loSh) = lv;
  }
}

// C fragment of A*B from LDS tiles. ar = local A row [0,32), bc = local B
// row [0,64) (B symmetric -> read by rows). 3 MFMAs per K-chunk (hi/lo split).
__device__ __forceinline__ f32x4 mmlds(const short* slds, int aoff, int boff,
                                       int ar, int bc, int kq) {
  f32x4 acc = {0.0f, 0.0f, 0.0f, 0.0f};
  const short* ah = slds + aoff + ar * 256;
  const short* al = ah + 32 * 256;       // A tiles are 32 rows
  const short* bh = slds + boff + bc * 256;
  const short* bl = bh + 64 * 256;       // B tiles are 64 rows
  const int ax = (ar & 7) << 3, bx = (bc & 7) << 3;
#pragma unroll
  for (int k0 = 0; k0 < 256; k0 += 32) {
    int ks = k0 + kq;
    bf16x8 Ah = *(const bf16x8*)(ah + (ks ^ ax));
    bf16x8 Al = *(const bf16x8*)(al + (ks ^ ax));
    bf16x8 Bh = *(const bf16x8*)(bh + (ks ^ bx));
    bf16x8 Bl = *(const bf16x8*)(bl + (ks ^ bx));
    acc = __builtin_amdgcn_mfma_f32_16x16x32_bf16(Ah, Bh, acc, 0, 0, 0);
    acc = __builtin_amdgcn_mfma_f32_16x16x32_bf16(Al, Bh, acc, 0, 0, 0);
    acc = __builtin_amdgcn_mfma_f32_16x16x32_bf16(Ah, Bl, acc, 0, 0, 0);
  }
  return acc;
}

// L2-LOCAL grid barrier (R11b verbatim; proven correct + hang-proof).
__device__ __forceinline__ void gridbar(int vbid, int lane, int wave, int* pgen) {
  asm volatile("s_waitcnt vmcnt(0) lgkmcnt(0)" ::: "memory");
  __syncthreads();
  const int n = ++(*pgen);
  if (wave == 0) {
    if (lane == 0) {
      volatile int* fp = (volatile int*)&g_flags[vbid];
      *fp = n;                          // plain write-through -> home L2
      __hip_atomic_store(&g_flagsA[vbid], n, __ATOMIC_RELAXED,
                         __HIP_MEMORY_SCOPE_AGENT);   // MALL mirror
    }
    int iter = 0;
    for (;;) {
      asm volatile("buffer_inv" ::: "memory");   // L1-only; L2 holds truth
      int fv = n;
      if (lane < NPART) {
        if (iter < 8192) {
          volatile int* fp = (volatile int*)&g_flags[lane];
          fv = *fp;
        } else {
          fv = __hip_atomic_load(&g_flagsA[lane], __ATOMIC_RELAXED,
                                 __HIP_MEMORY_SCOPE_AGENT);  // MALL fallback
        }
      }
      if (__all(fv >= n)) break;
      ++iter;
      __builtin_amdgcn_s_sleep(1);
    }
  }
  __syncthreads();
  __builtin_amdgcn_sched_barrier(0);
}

// Chebyshev-PS regrouping (unchanged).
__device__ void regroup_d(const double* c, float* outp, int s, int m) {
  double al[64];
  for (int i = m; i >= 1; i--)
    for (int r = 0; r < s; r++) {
      double v;
      if (r == 0) v = c[s * i];
      else v = 2.0 * c[s * i + r] - ((i == m) ? 0.0 : al[s * (i + 1) + (s - r)]);
      al[s * i + r] = v;
    }
  al[0] = c[0];
  for (int r = 1; r < s; r++) al[r] = c[r] - 0.5 * al[s + (s - r)];
  int tot = s * (m + 1);
  for (int j = 0; j < tot; j++) outp[j] = (float)al[j];
}

__global__ void setup_kernel(const float* __restrict__ wts) {
  const int k = blockIdx.x;
  const int lane = threadIdx.x;
  __shared__ double s_fv[128];
  __shared__ double s_c[64];
  const double PI = 3.14159265358979323846;
  if (k < 256) {
    double w0 = (double)wts[2 * k], w1 = (double)wts[2 * k + 1];
    double t = 1.0 / (1.0 + exp(w0 - w1));     // softmax(...)[:,1]
    double c0 = 0.5 * ((double)AS_ + (double)BS_), h0 = 0.5 * ((double)BS_ - (double)AS_);
    for (int i = lane; i < 128; i += 64) {
      double th = (i + 0.5) * PI / 128.0;
      double y = c0 + h0 * cos(th);
      s_fv[i] = pow(y, t);
    }
    __syncthreads();
    if (lane < 40) {
      double s = 0.0;
      for (int i = 0; i < 128; i++) {
        double th = (i + 0.5) * PI / 128.0;
        s += s_fv[i] * cos((double)lane * th);
      }
      s_c[lane] = s * ((lane == 0) ? 1.0 : 2.0) / 128.0;
    }
    __syncthreads();
    if (lane == 0) regroup_d(s_c, g_aS[k], 8, 4);
  } else {
    double c0 = 0.5 * ((double)AM + (double)BM), h0 = 0.5 * ((double)BM - (double)AM);
    for (int i = lane; i < 128; i += 64) {
      double th = (i + 0.5) * PI / 128.0;
      double y = c0 + h0 * cos(th);
      s_fv[i] = 1.0 / sqrt(y);
    }
    __syncthreads();
    if (lane < 12) {
      double s = 0.0;
      for (int i = 0; i < 128; i++) {
        double th = (i + 0.5) * PI / 128.0;
        s += s_fv[i] * cos((double)lane * th);
      }
      s_c[lane] = s * ((lane == 0) ? 1.0 : 2.0) / 128.0;
    }
    __syncthreads();
    if (lane == 0) {
      regroup_d(s_c, g_aM, 4, 2);
      g_slot.v = 0; g_xcd = -1;
      for (int j = 0; j < 32; j++) { g_flags[j] = 0; g_flagsA[j] = 0; }
    }
  }
}

// 32 participants x 512 thr; 128KB LDS -> 1 block/CU across the home XCD's
// 32 CUs. 256 waves = one 16x16 C-tile per wave.
__global__ void __launch_bounds__(512, 1) frechet_kernel(const float* __restrict__ f,
                                                         float* __restrict__ out) {
  __shared__ int s_vbid;
  __shared__ short slds[65536];   // 128 KB: B(64KB) + A1(32KB) + A2(32KB)
  int xcc;
  asm volatile("s_getreg_b32 %0, hwreg(HW_REG_XCC_ID)" : "=s"(xcc));
  xcc &= 7;
  if (threadIdx.x == 0) {
    int expected = -1;
    bool won = __hip_atomic_compare_exchange_strong(
        &g_xcd, &expected, xcc, __ATOMIC_RELAXED, __ATOMIC_RELAXED,
        __HIP_MEMORY_SCOPE_AGENT);
    int chosen = won ? xcc : expected;
    int slot = -1;
    if (chosen == xcc)
      slot = __hip_atomic_fetch_add(&g_slot.v, 1, __ATOMIC_RELAXED,
                                    __HIP_MEMORY_SCOPE_AGENT);
    s_vbid = slot;
  }
  __syncthreads();
  const int vbid = s_vbid;
  if (vbid < 0 || vbid >= NPART) return;

  const int tid = threadIdx.x;
  const int lane = tid & 63, wave = tid >> 6;
  const int tr = (vbid >> 2) * 32, tc = (vbid & 3) * 64;  // 8x4 grid of 32x64
  const int sr = (wave >> 2) * 16, sc = (wave & 3) * 16;  // 2x4 waves of 16x16
  const int ar = sr + (lane & 15);            // LOCAL A row [0,32)
  const int bc = sc + (lane & 15);            // LOCAL B row [0,64)
  const int colg = tc + bc;                   // global C col
  const int kq = (lane >> 4) * 8;             // K sub-offset within chunk
  const int row0 = tr + sr + (lane >> 4) * 4; // global C rows for acc[0..3]
  const int fbase = (vbid * 512 + tid) * 4;
  int gen = 0;

  const float sM = 2.0f / (BM - AM), cM = 0.5f * (AM + BM);
  const float sS = 2.0f / (BS_ - AS_), cS = 0.5f * (AS_ + BS_);

  // Register-carried per-thread values (produced by THIS thread earlier).
  float xmr[4], u2r[4], cbar[4], qm1r[4], qm0r[4], isqr[4];
  float xsr[4], v2r[4], v3r[4], v4r[4];
  float qs3r[4], qs2r[4], qs1r[4], qs0r[4], sbar[4], sbbr[4], sbcr[4];

  // Init: XM = sM*(1-cM)*I; stage f_0 into bf16 planes.
  {
    float4 f0 = *(const float4*)(f + fbase);
    float fv[4] = {f0.x, f0.y, f0.z, f0.w};
#pragma unroll
    for (int r = 0; r < 4; r++) {
      int row = row0 + r, idx = row * 256 + colg;
      xmr[r] = (row == colg) ? sM * (1.0f - cM) : 0.0f;
      wrm(iXM, idx, xmr[r]);
      wrm(iFK, fbase + r, fv[r]);
    }
  }
  gridbar(vbid, lane, wave, &gen);

  for (int k = 0; k < 256; k++) {
    const float* aS = g_aS[k];
    const float* aM = g_aM;

    { // r1: U2 = 2*XM*XM - I.  A1<-XM(tr) [lives through r5], B<-XM(tc)
      stage(slds, iXM, tr, 32, LDS_A1, tid);
      stage(slds, iXM, tc, 64, LDS_B, tid);
      __syncthreads();
      f32x4 a = mmlds(slds, LDS_A1, LDS_B, ar, bc, kq);
#pragma unroll
      for (int r = 0; r < 4; r++) {
        int row = row0 + r, idx = row * 256 + colg;
        u2r[r] = 2.0f * a[r] - ((row == colg) ? 1.0f : 0.0f);
        wrm(iU2, idx, u2r[r]);
      }
    }
    gridbar(vbid, lane, wave, &gen);
    { // r2: U3(regs), U4, CBA.  A2<-U2(tr), B<-U2(tc); A1 keeps XM.
      stage(slds, iU2, tr, 32, LDS_A2, tid);
      stage(slds, iU2, tc, 64, LDS_B, tid);
      __syncthreads();
      f32x4 a3 = mmlds(slds, LDS_A1, LDS_B, ar, bc, kq);  // XM*U2
      f32x4 a4 = mmlds(slds, LDS_A2, LDS_B, ar, bc, kq);  // U2*U2
#pragma unroll
      for (int r = 0; r < 4; r++) {
        int row = row0 + r, idx = row * 256 + colg;
        float dI = (row == colg) ? 1.0f : 0.0f;
        float xm = xmr[r], u2 = u2r[r];
        float u3 = 2.0f * a3[r] - xm;
        wrm(iU4, idx, 2.0f * a4[r] - dI);
        cbar[r] = aM[8] * dI + aM[9] * xm + aM[10] * u2 + aM[11] * u3;
        wrm(iCBA, idx, cbar[r]);
        qm1r[r] = aM[4] * dI + aM[5] * xm + aM[6] * u2 + aM[7] * u3;
        qm0r[r] = aM[0] * dI + aM[1] * xm + aM[2] * u2 + aM[3] * u3;
      }
    }
    gridbar(vbid, lane, wave, &gen);
    { // r3: CBB = 2*U4*CBA + Q1.  A2<-U4(tr) [lives r3-r4], B<-CBA(tc).
      stage(slds, iU4, tr, 32, LDS_A2, tid);
      stage(slds, iCBA, tc, 64, LDS_B, tid);
      __syncthreads();
      f32x4 a = mmlds(slds, LDS_A2, LDS_B, ar, bc, kq);
#pragma unroll
      for (int r = 0; r < 4; r++) {
        int idx = (row0 + r) * 256 + colg;
        wrm(iCBB, idx, 2.0f * a[r] + qm1r[r]);
      }
    }
    gridbar(vbid, lane, wave, &gen);
    { // r4: ISQ = U4*CBB - CBA + Q0.  B<-CBB only (A2 keeps U4).
      stage(slds, iCBB, tc, 64, LDS_B, tid);
      __syncthreads();
      f32x4 a = mmlds(slds, LDS_A2, LDS_B, ar, bc, kq);
#pragma unroll
      for (int r = 0; r < 4; r++) {
        int idx = (row0 + r) * 256 + colg;
        isqr[r] = a[r] - cbar[r] + qm0r[r];
        wrm(iISQ, idx, isqr[r]);
      }
    }
    gridbar(vbid, lane, wave, &gen);
    { // r5: SQ = (1/sM)*XM*ISQ + cM*ISQ ; G = ISQ*FK.  Two phases.
      stage(slds, iISQ, tr, 32, LDS_A2, tid);   // ph1: A2<-ISQ, B<-FK
      stage(slds, iFK, tc, 64, LDS_B, tid);
      __syncthreads();
      f32x4 b = mmlds(slds, LDS_A2, LDS_B, ar, bc, kq);   // ISQ*FK
      __syncthreads();
      stage(slds, iISQ, tc, 64, LDS_B, tid);    // ph2: B<-ISQ [lives to r6]
      __syncthreads();
      f32x4 a = mmlds(slds, LDS_A1, LDS_B, ar, bc, kq);   // XM*ISQ
#pragma unroll
      for (int r = 0; r < 4; r++) {
        int idx = (row0 + r) * 256 + colg;
        wrm(iSQ, idx, a[r] * (1.0f / sM) + cM * isqr[r]);
        wrm(iG, idx, b[r]);
      }
    }
    gridbar(vbid, lane, wave, &gen);
    { // r6: XS = sS*(G*ISQ) - sS*cS*I.  A2<-G(tr); B keeps ISQ(tc).
      stage(slds, iG, tr, 32, LDS_A2, tid);
      __syncthreads();
      f32x4 a = mmlds(slds, LDS_A2, LDS_B, ar, bc, kq);
#pragma unroll
      for (int r = 0; r < 4; r++) {
        int row = row0 + r, idx = row * 256 + colg;
        xsr[r] = sS * a[r] - sS * cS * ((row == colg) ? 1.0f : 0.0f);
        wrm(iXS, idx, xsr[r]);
      }
    }
    gridbar(vbid, lane, wave, &gen);
    { // r7: V2 = 2*XS*XS - I.  A1<-XS(tr) [XM dead], B<-XS(tc).
      stage(slds, iXS, tr, 32, LDS_A1, tid);
      stage(slds, iXS, tc, 64, LDS_B, tid);
      __syncthreads();
      f32x4 a = mmlds(slds, LDS_A1, LDS_B, ar, bc, kq);
#pragma unroll
      for (int r = 0; r < 4; r++) {
        int row = row0 + r, idx = row * 256 + colg;
        v2r[r] = 2.0f * a[r] - ((row == colg) ? 1.0f : 0.0f);
        wrm(iV2, idx, v2r[r]);
      }
    }
    gridbar(vbid, lane, wave, &gen);
    { // r8: V3 = 2*XS*V2 - XS ; V4 = 2*V2*V2 - I.  A2<-V2(tr), B<-V2(tc).
      stage(slds, iV2, tr, 32, LDS_A2, tid);
      stage(slds, iV2, tc, 64, LDS_B, tid);
      __syncthreads();
      f32x4 a = mmlds(slds, LDS_A1, LDS_B, ar, bc, kq);   // XS*V2
      f32x4 b = mmlds(slds, LDS_A2, LDS_B, ar, bc, kq);   // V2*V2
#pragma unroll
      for (int r = 0; r < 4; r++) {
        int row = row0 + r, idx = row * 256 + colg;
        float dI = (row == colg) ? 1.0f : 0.0f;
        v3r[r] = 2.0f * a[r] - xsr[r];
        v4r[r] = 2.0f * b[r] - dI;
        wrm(iV3, idx, v3r[r]);
        wrm(iV4, idx, v4r[r]);
      }
    }
    gridbar(vbid, lane, wave, &gen);
    { // r9: T5..T8, V8, q4->SBA, Q3..Q0 regs; f_{k+1} prefetch. Two phases.
      f32x4 fq;
      if (k < 255) {
        const f32x4* fp = (const f32x4*)(f + (size_t)(k + 1) * 65536 + fbase);
        fq = __builtin_nontemporal_load(fp);
      } else {
        fq = (f32x4){0.f, 0.f, 0.f, 0.f};
      }
      stage(slds, iV3, tr, 32, LDS_A1, tid);    // ph1: A1<-V3, B<-V3
      stage(slds, iV3, tc, 64, LDS_B, tid);
      __syncthreads();
      f32x4 a5 = mmlds(slds, LDS_A2, LDS_B, ar, bc, kq);  // V2*V3 (A2=V2)
      f32x4 a6 = mmlds(slds, LDS_A1, LDS_B, ar, bc, kq);  // V3*V3
      __syncthreads();
      stage(slds, iV4, tr, 32, LDS_A2, tid);    // ph2: A2<-V4, B<-V4
      stage(slds, iV4, tc, 64, LDS_B, tid);
      __syncthreads();
      f32x4 a7 = mmlds(slds, LDS_A1, LDS_B, ar, bc, kq);  // V3*V4
      f32x4 a8 = mmlds(slds, LDS_A2, LDS_B, ar, bc, kq);  // V4*V4
#pragma unroll
      for (int r = 0; r < 4; r++) {
        int row = row0 + r, idx = row * 256 + colg;
        float dI = (row == colg) ? 1.0f : 0.0f;
        float xs = xsr[r], v2 = v2r[r], v3 = v3r[r], v4 = v4r[r];
        float v5 = 2.0f * a5[r] - xs;
        float v6 = 2.0f * a6[r] - dI;
        float v7 = 2.0f * a7[r] - xs;
        float v8 = 2.0f * a8[r] - dI;
        wrm(iV8, idx, v8);
        sbar[r] = aS[32] * dI + aS[33] * xs + aS[34] * v2 + aS[35] * v3 +
                  aS[36] * v4 + aS[37] * v5 + aS[38] * v6 + aS[39] * v7;
        wrm(iSBA, idx, sbar[r]);
        qs3r[r] = aS[24] * dI + aS[25] * xs + aS[26] * v2 + aS[27] * v3 +
                  aS[28] * v4 + aS[29] * v5 + aS[30] * v6 + aS[31] * v7;
        qs2r[r] = aS[16] * dI + aS[17] * xs + aS[18] * v2 + aS[19] * v3 +
                  aS[20] * v4 + aS[21] * v5 + aS[22] * v6 + aS[23] * v7;
        qs1r[r] = aS[8] * dI + aS[9] * xs + aS[10] * v2 + aS[11] * v3 +
                  aS[12] * v4 + aS[13] * v5 + aS[14] * v6 + aS[15] * v7;
        qs0r[r] = aS[0] * dI + aS[1] * xs + aS[2] * v2 + aS[3] * v3 +
                  aS[4] * v4 + aS[5] * v5 + aS[6] * v6 + aS[7] * v7;
      }
      if (k < 255) {
        float fv[4] = {fq[0], fq[1], fq[2], fq[3]};
#pragma unroll
        for (int r = 0; r < 4; r++) wrm(iFK, fbase + r, fv[r]);
      }
    }
    gridbar(vbid, lane, wave, &gen);
    { // r10: b3 = 2*V8*b4 + Q3.  A1<-V8(tr) [lives r10-r13], B<-SBA(tc).
      stage(slds, iV8, tr, 32, LDS_A1, tid);
      stage(slds, iSBA, tc, 64, LDS_B, tid);
      __syncthreads();
      f32x4 a = mmlds(slds, LDS_A1, LDS_B, ar, bc, kq);
#pragma unroll
      for (int r = 0; r < 4; r++) {
        int idx = (row0 + r) * 256 + colg;
        sbbr[r] = 2.0f * a[r] + qs3r[r];
        wrm(iSBB, idx, sbbr[r]);
      }
    }
    gridbar(vbid, lane, wave, &gen);
    { // r11: b2 = 2*V8*b3 - b4 + Q2.  B<-SBB only.
      stage(slds, iSBB, tc, 64, LDS_B, tid);
      __syncthreads();
      f32x4 a = mmlds(slds, LDS_A1, LDS_B, ar, bc, kq);
#pragma unroll
      for (int r = 0; r < 4; r++) {
        int idx = (row0 + r) * 256 + colg;
        sbcr[r] = 2.0f * a[r] - sbar[r] + qs2r[r];
        wrm(iSBC, idx, sbcr[r]);
      }
    }
    gridbar(vbid, lane, wave, &gen);
    { // r12: b1 = 2*V8*b2 - b3 + Q1.  B<-SBC only.
      stage(slds, iSBC, tc, 64, LDS_B, tid);
      __syncthreads();
      f32x4 a = mmlds(slds, LDS_A1, LDS_B, ar, bc, kq);
#pragma unroll
      for (int r = 0; r < 4; r++) {
        int idx = (row0 + r) * 256 + colg;
        wrm(iSBA, idx, 2.0f * a[r] - sbbr[r] + qs1r[r]);
      }
    }
    gridbar(vbid, lane, wave, &gen);
    { // r13: P = V8*b1 - b2 + Q0.  B<-SBA (new value) only.
      stage(slds, iSBA, tc, 64, LDS_B, tid);
      __syncthreads();
      f32x4 a = mmlds(slds, LDS_A1, LDS_B, ar, bc, kq);
#pragma unroll
      for (int r = 0; r < 4; r++) {
        int idx = (row0 + r) * 256 + colg;
        wrm(iPP, idx, a[r] - sbcr[r] + qs0r[r]);
      }
    }
    gridbar(vbid, lane, wave, &gen);
    { // r14: HH = SQ*P.  A1<-SQ(tr), B<-PP(tc).
      stage(slds, iSQ, tr, 32, LDS_A1, tid);
      stage(slds, iPP, tc, 64, LDS_B, tid);
      __syncthreads();
      f32x4 a = mmlds(slds, LDS_A1, LDS_B, ar, bc, kq);
#pragma unroll
      for (int r = 0; r < 4; r++) {
        int idx = (row0 + r) * 256 + colg;
        wrm(iHH, idx, a[r]);
      }
    }
    gridbar(vbid, lane, wave, &gen);
    { // r15: Mn = HH*SQ -> out[k] (fp32, NT); XM_next = sM*(Mn - cM*I).
      stage(slds, iHH, tr, 32, LDS_A1, tid);
      stage(slds, iSQ, tc, 64, LDS_B, tid);
      __syncthreads();
      f32x4 a = mmlds(slds, LDS_A1, LDS_B, ar, bc, kq);
      float* ok = out + (size_t)k * 65536;
#pragma unroll
      for (int r = 0; r < 4; r++) {
        int row = row0 + r, idx = row * 256 + colg;
        float dI = (row == colg) ? 1.0f : 0.0f;
        float v = a[r];
        __builtin_nontemporal_store(v, ok + idx);
        xmr[r] = sM * (v - cM * dI);
        wrm(iXM, idx, xmr[r]);
      }
    }
    gridbar(vbid, lane, wave, &gen);
  }
}

extern "C" void kernel_launch(void* const* d_in, const int* in_sizes, int n_in,
                              void* d_out, int out_size, void* d_ws, size_t ws_size,
                              hipStream_t stream) {
  (void)in_sizes; (void)n_in; (void)d_ws; (void)ws_size; (void)out_size;
  const float* f = (const float*)d_in[0];
  const float* w = (const float*)d_in[1];
  float* out = (float*)d_out;

  setup_kernel<<<dim3(257), dim3(64), 0, stream>>>(w);

  // 1024 probe blocks; first block CAS-elects its XCD as home; first 32
  // home-XCD blocks participate (128KB LDS -> 1 block/CU). Barrier flags in
  // home L2 with MALL-mirrored fallback: broken placement -> visible failure,
  // never a hang.
  frechet_kernel<<<dim3(1024), dim3(512), 0, stream>>>(f, out);
}